// Round 3
// baseline (1444.224 us; speedup 1.0000x reference)
//
#include <hip/hip_runtime.h>
#include <math.h>

// GCN 2-layer on MI355X. N=100000, E=3200000, F_IN=256, HID=32, F_OUT=64.
// Bucket strategy: sort edges into 64-node destination buckets (coarse counting
// sort, per-block reserved writes -> fully-combined lines). Aggregate with one
// block per bucket into an LDS accumulator (no global float atomics, no CSR).
// dinv folded into source: agg(h)[i] = dinv[i] * (sum_{j->i} g[j] + g[i]), g = dinv.h

#define SHIFT 6
#define S 64
#define MAXNB 1600

__global__ void k_zero(int* p, int n) {
    int i = blockIdx.x * blockDim.x + threadIdx.x;
    if (i < n) p[i] = 0;
}

// global bucket counts via per-block LDS histogram
__global__ void k_bhist(const int* __restrict__ cols, int* __restrict__ bcnt,
                        int e, int nb) {
    __shared__ int h[MAXNB];
    for (int i = threadIdx.x; i < nb; i += blockDim.x) h[i] = 0;
    __syncthreads();
    for (int i = blockIdx.x * blockDim.x + threadIdx.x; i < e; i += gridDim.x * blockDim.x)
        atomicAdd(&h[cols[i] >> SHIFT], 1);
    __syncthreads();
    for (int i = threadIdx.x; i < nb; i += blockDim.x)
        if (h[i]) atomicAdd(&bcnt[i], h[i]);
}

// exclusive scan of nb (<2048) bucket counts; one block of 1024
__global__ void k_bscan(const int* __restrict__ bcnt, int* __restrict__ bptr,
                        int* __restrict__ bfill, int nb, int e) {
    __shared__ int sh[1024];
    int tid = threadIdx.x;
    int a = (2 * tid     < nb) ? bcnt[2 * tid]     : 0;
    int b = (2 * tid + 1 < nb) ? bcnt[2 * tid + 1] : 0;
    sh[tid] = a + b;
    __syncthreads();
    for (int off = 1; off < 1024; off <<= 1) {
        int t = (tid >= off) ? sh[tid - off] : 0;
        __syncthreads();
        sh[tid] += t;
        __syncthreads();
    }
    int excl = sh[tid] - (a + b);
    if (2 * tid < nb)     { bptr[2 * tid] = excl;         bfill[2 * tid] = excl; }
    if (2 * tid + 1 < nb) { bptr[2 * tid + 1] = excl + a; bfill[2 * tid + 1] = excl + a; }
    if (tid == 0) bptr[nb] = e;
}

// bucket the edges; per-block reservation so each bucket range is written in
// large sequential runs by one block (full-line write combining)
__global__ void k_bscatter(const int* __restrict__ rows, const int* __restrict__ cols,
                           int* bfill, int2* __restrict__ pairs, int e, int nb, int chunk) {
    __shared__ int hist[MAXNB];
    int tid = threadIdx.x;
    for (int i = tid; i < nb; i += blockDim.x) hist[i] = 0;
    __syncthreads();
    int start = blockIdx.x * chunk;
    int end = min(e, start + chunk);
    for (int i = start + tid; i < end; i += blockDim.x)
        atomicAdd(&hist[cols[i] >> SHIFT], 1);
    __syncthreads();
    for (int i = tid; i < nb; i += blockDim.x) {
        int c = hist[i];
        if (c) hist[i] = atomicAdd(&bfill[i], c);   // hist[] becomes per-block base
    }
    __syncthreads();
    for (int i = start + tid; i < end; i += blockDim.x) {
        int r = rows[i], c = cols[i];
        int pos = atomicAdd(&hist[c >> SHIFT], 1);
        pairs[pos] = make_int2(r, c);
    }
}

// per-bucket degree histogram -> dinv (no global atomics)
__global__ void k_bdeg(const int2* __restrict__ pairs, const int* __restrict__ bptr,
                       float* __restrict__ dinv, int n) {
    __shared__ int cnt[S];
    int tid = threadIdx.x, b = blockIdx.x;
    if (tid < S) cnt[tid] = 0;
    __syncthreads();
    int s = bptr[b], e = bptr[b + 1];
    for (int t = s + tid; t < e; t += blockDim.x)
        atomicAdd(&cnt[pairs[t].y & (S - 1)], 1);
    __syncthreads();
    int node = (b << SHIFT) + tid;
    if (tid < S && node < n) dinv[node] = rsqrtf((float)(cnt[tid] + 1));
}

// g1 = dinv (.) (x @ W1): LDS-tiled, 32 nodes/block
__launch_bounds__(256)
__global__ void k_xw_g(const float4* __restrict__ x4, const float* __restrict__ W1,
                       const float* __restrict__ dinv, float* __restrict__ g1, int n) {
    __shared__ float xs[32 * 260];
    int tid = threadIdx.x;
    int nb = blockIdx.x * 32;
#pragma unroll
    for (int t = 0; t < 8; ++t) {
        int idx = tid + t * 256;
        int row = idx >> 6, c4 = idx & 63;
        float4 v = (nb + row < n) ? x4[(size_t)(nb + row) * 64 + c4]
                                  : make_float4(0.f, 0.f, 0.f, 0.f);
        *reinterpret_cast<float4*>(&xs[row * 260 + c4 * 4]) = v;
    }
    __syncthreads();
    int row = tid >> 3, k4 = tid & 7;
    int node = nb + row;
    if (node >= n) return;
    float s0 = 0.f, s1 = 0.f, s2 = 0.f, s3 = 0.f;
#pragma unroll 8
    for (int i = 0; i < 256; ++i) {
        float xv = xs[row * 260 + i];
        float4 w = *reinterpret_cast<const float4*>(&W1[i * 32 + k4 * 4]);
        s0 += xv * w.x; s1 += xv * w.y; s2 += xv * w.z; s3 += xv * w.w;
    }
    float d = dinv[node];
    *reinterpret_cast<float4*>(&g1[(size_t)node * 32 + k4 * 4]) =
        make_float4(d * s0, d * s1, d * s2, d * s3);
}

// layer-1 aggregate into LDS acc, epilogue: g2 = dinv (.) relu(dinv*(acc+self) + b1)
__launch_bounds__(256)
__global__ void k_agg1(const float* __restrict__ g1, const int2* __restrict__ pairs,
                       const int* __restrict__ bptr, const float* __restrict__ dinv,
                       const float* __restrict__ b1, float* __restrict__ g2, int n) {
    __shared__ float acc[S * 32];
    int tid = threadIdx.x, b = blockIdx.x;
    for (int i = tid; i < S * 32; i += 256) acc[i] = 0.f;
    __syncthreads();
    int s = bptr[b], e = bptr[b + 1];
    int sub = tid >> 5, k = tid & 31;
    for (int t = s + sub; t < e; t += 8) {
        int2 p = pairs[t];
        float v = g1[((size_t)p.x << 5) + k];        // coalesced 128B gather
        atomicAdd(&acc[((p.y & (S - 1)) << 5) + k], v);  // lane k -> bank k
    }
    __syncthreads();
    for (int i = tid; i < S * 32; i += 256) {
        int node = (b << SHIFT) + (i >> 5);
        if (node >= n) break;
        float d = dinv[node];
        float h = fmaf(d, acc[i] + g1[((size_t)node << 5) + (i & 31)], b1[i & 31]);
        h = h > 0.f ? h : 0.f;
        g2[((size_t)node << 5) + (i & 31)] = d * h;
    }
}

// layer-2 aggregate + fused W2 projection: out = (dinv*(acc+self)) @ W2 + b2
__launch_bounds__(256)
__global__ void k_agg2(const float* __restrict__ g2, const int2* __restrict__ pairs,
                       const int* __restrict__ bptr, const float* __restrict__ dinv,
                       const float* __restrict__ W2, const float* __restrict__ b2,
                       float* __restrict__ out, int n) {
    __shared__ float acc[S * 32];     // 8KB: fr tile
    __shared__ float w2s[32 * 64];    // 8KB
    int tid = threadIdx.x, b = blockIdx.x;
    for (int i = tid; i < S * 32; i += 256) { acc[i] = 0.f; w2s[i] = W2[i]; }
    __syncthreads();
    int s = bptr[b], e = bptr[b + 1];
    int sub = tid >> 5, k = tid & 31;
    for (int t = s + sub; t < e; t += 8) {
        int2 p = pairs[t];
        float v = g2[((size_t)p.x << 5) + k];
        atomicAdd(&acc[((p.y & (S - 1)) << 5) + k], v);
    }
    __syncthreads();
    // finalize fr = dinv*(acc + self) in place
    for (int i = tid; i < S * 32; i += 256) {
        int node = (b << SHIFT) + (i >> 5);
        float v = 0.f;
        if (node < n) v = dinv[node] * (acc[i] + g2[((size_t)node << 5) + (i & 31)]);
        acc[i] = v;
    }
    __syncthreads();
    // projection: j = lane (conflict-free w2s), m uniform per wave (acc broadcast)
    int j = tid & 63, mg = tid >> 6;   // mg in 0..3
    for (int mm = 0; mm < 16; ++mm) {
        int m = mg * 16 + mm;
        int node = (b << SHIFT) + m;
        float sacc = b2[j];
#pragma unroll
        for (int i = 0; i < 32; ++i)
            sacc = fmaf(acc[m * 32 + i], w2s[i * 64 + j], sacc);
        if (node < n) out[(size_t)node * 64 + j] = sacc;
    }
}

extern "C" void kernel_launch(void* const* d_in, const int* in_sizes, int n_in,
                              void* d_out, int out_size, void* d_ws, size_t ws_size,
                              hipStream_t stream) {
    const float* x  = (const float*)d_in[0];
    const int*   ei = (const int*)d_in[1];
    const float* W1 = (const float*)d_in[2];
    const float* b1 = (const float*)d_in[3];
    const float* W2 = (const float*)d_in[4];
    const float* b2 = (const float*)d_in[5];
    float* out = (float*)d_out;

    const int N = in_sizes[0] / 256;
    const int E = in_sizes[1] / 2;
    const int* rows = ei;        // edge_index[0] (source)
    const int* cols = ei + E;    // edge_index[1] (dest)
    const int NB = (N + S - 1) >> SHIFT;   // 1563 buckets

    // ws layout (4B units): pairs[2E] | g1[N*32] | g2[N*32] | dinv[N] | bptr[NB+1] | bcnt[NB] | bfill[NB]
    int2*  pairs = (int2*)d_ws;
    float* g1    = (float*)(pairs + E);
    float* g2    = g1 + (size_t)N * 32;
    float* dinv  = g2 + (size_t)N * 32;
    int*   bptr  = (int*)(dinv + N);
    int*   bcnt  = bptr + (NB + 1);
    int*   bfill = bcnt + NB;

    const int B = 256;
    const int chunk = (E + 255) / 256;

    k_zero<<<(NB + B - 1) / B, B, 0, stream>>>(bcnt, NB);
    k_bhist<<<256, B, 0, stream>>>(cols, bcnt, E, NB);
    k_bscan<<<1, 1024, 0, stream>>>(bcnt, bptr, bfill, NB, E);
    k_bscatter<<<256, B, 0, stream>>>(rows, cols, bfill, pairs, E, NB, chunk);
    k_bdeg<<<NB, B, 0, stream>>>(pairs, bptr, dinv, N);
    k_xw_g<<<(N + 31) / 32, B, 0, stream>>>((const float4*)x, W1, dinv, g1, N);
    k_agg1<<<NB, B, 0, stream>>>(g1, pairs, bptr, dinv, b1, g2, N);
    k_agg2<<<NB, B, 0, stream>>>(g2, pairs, bptr, dinv, W2, b2, out, N);
}

// Round 4
// 335.249 us; speedup vs baseline: 4.3079x; 4.3079x over previous
//
#include <hip/hip_runtime.h>
#include <math.h>

// GCN 2-layer on MI355X. N=100000, E=3200000, F_IN=256, HID=32, F_OUT=64.
// Pipeline: coarse bucket sort by dest (write-combined, packed row<<6|col6),
// per-bucket LDS fine sort -> per-node CSR + dinv, then gather-based
// aggregations (float4 lanes, 4-wide unroll). No global float atomics.
// dinv folded into source: agg(h)[i] = dinv[i]*(sum_{j->i} g[j] + g[i]), g = dinv.h

#define SHIFT 6
#define S 64
#define MAXNB 1600
#define CAP 6144

__device__ inline float4 add4(float4 a, float4 b) {
    return make_float4(a.x + b.x, a.y + b.y, a.z + b.z, a.w + b.w);
}

__global__ void k_zero(int* p, int n) {
    int i = blockIdx.x * blockDim.x + threadIdx.x;
    if (i < n) p[i] = 0;
}

// global bucket counts via per-block LDS histogram
__global__ void k_bhist(const int* __restrict__ cols, int* __restrict__ bcnt,
                        int e, int nb) {
    __shared__ int h[MAXNB];
    for (int i = threadIdx.x; i < nb; i += blockDim.x) h[i] = 0;
    __syncthreads();
    for (int i = blockIdx.x * blockDim.x + threadIdx.x; i < e; i += gridDim.x * blockDim.x)
        atomicAdd(&h[cols[i] >> SHIFT], 1);
    __syncthreads();
    for (int i = threadIdx.x; i < nb; i += blockDim.x)
        if (h[i]) atomicAdd(&bcnt[i], h[i]);
}

// exclusive scan of nb (<=2048) bucket counts
__global__ void k_bscan(const int* __restrict__ bcnt, int* __restrict__ bptr,
                        int* __restrict__ bfill, int nb, int e) {
    __shared__ int sh[1024];
    int tid = threadIdx.x;
    int a = (2 * tid     < nb) ? bcnt[2 * tid]     : 0;
    int b = (2 * tid + 1 < nb) ? bcnt[2 * tid + 1] : 0;
    sh[tid] = a + b;
    __syncthreads();
    for (int off = 1; off < 1024; off <<= 1) {
        int t = (tid >= off) ? sh[tid - off] : 0;
        __syncthreads();
        sh[tid] += t;
        __syncthreads();
    }
    int excl = sh[tid] - (a + b);
    if (2 * tid < nb)     { bptr[2 * tid] = excl;         bfill[2 * tid] = excl; }
    if (2 * tid + 1 < nb) { bptr[2 * tid + 1] = excl + a; bfill[2 * tid + 1] = excl + a; }
    if (tid == 0) bptr[nb] = e;
}

// bucket the edges, packed (row<<6)|(col&63); per-block reservation so each
// bucket range is written in sequential runs (write combining)
__global__ void k_bscatter(const int* __restrict__ rows, const int* __restrict__ cols,
                           int* bfill, unsigned* __restrict__ pk, int e, int nb, int chunk) {
    __shared__ int hist[MAXNB];
    int tid = threadIdx.x;
    for (int i = tid; i < nb; i += blockDim.x) hist[i] = 0;
    __syncthreads();
    int start = blockIdx.x * chunk;
    int end = min(e, start + chunk);
    for (int i = start + tid; i < end; i += blockDim.x)
        atomicAdd(&hist[cols[i] >> SHIFT], 1);
    __syncthreads();
    for (int i = tid; i < nb; i += blockDim.x) {
        int c = hist[i];
        if (c) hist[i] = atomicAdd(&bfill[i], c);   // hist[] becomes per-block base
    }
    __syncthreads();
    for (int i = start + tid; i < end; i += blockDim.x) {
        int r = rows[i], c = cols[i];
        int pos = atomicAdd(&hist[c >> SHIFT], 1);
        pk[pos] = ((unsigned)r << SHIFT) | (unsigned)(c & (S - 1));
    }
}

// per-bucket fine sort: histogram -> scan -> stage rows sorted-by-node in LDS
// -> contiguous in-place write-back. Also emits per-node CSR ptr + dinv.
__global__ void k_fine(unsigned* pk, const int* __restrict__ bptr,
                       int* __restrict__ ptr, float* __restrict__ dinv, int n, int nb) {
    __shared__ int cnt[S], base[S], fill[S];
    __shared__ int stage[CAP];
    int tid = threadIdx.x, b = blockIdx.x;
    if (tid < S) cnt[tid] = 0;
    __syncthreads();
    int s = bptr[b], e = bptr[b + 1], L = e - s;
    for (int t = s + tid; t < e; t += 256) atomicAdd(&cnt[pk[t] & (S - 1)], 1);
    __syncthreads();
    if (tid == 0) {
        int run = 0;
        for (int i = 0; i < S; ++i) { base[i] = run; fill[i] = run; run += cnt[i]; }
    }
    __syncthreads();
    if (tid < S) {
        int node = (b << SHIFT) + tid;
        if (node < n) {
            ptr[node] = s + base[tid];
            dinv[node] = rsqrtf((float)(cnt[tid] + 1));
        }
    }
    if (tid == 0 && b == nb - 1) ptr[n] = e;
    for (int t = s + tid; t < e; t += 256) {
        unsigned p = pk[t];
        int pos = atomicAdd(&fill[p & (S - 1)], 1);
        if (pos < CAP) stage[pos] = (int)(p >> SHIFT);
    }
    __syncthreads();
    int M = L < CAP ? L : CAP;
    for (int i = tid; i < M; i += 256) pk[s + i] = (unsigned)stage[i];
}

// g1 = dinv (.) (x @ W1): LDS-tiled, 32 nodes/block
__launch_bounds__(256)
__global__ void k_xw_g(const float4* __restrict__ x4, const float* __restrict__ W1,
                       const float* __restrict__ dinv, float* __restrict__ g1, int n) {
    __shared__ float xs[32 * 260];
    int tid = threadIdx.x;
    int nb = blockIdx.x * 32;
#pragma unroll
    for (int t = 0; t < 8; ++t) {
        int idx = tid + t * 256;
        int row = idx >> 6, c4 = idx & 63;
        float4 v = (nb + row < n) ? x4[(size_t)(nb + row) * 64 + c4]
                                  : make_float4(0.f, 0.f, 0.f, 0.f);
        *reinterpret_cast<float4*>(&xs[row * 260 + c4 * 4]) = v;
    }
    __syncthreads();
    int row = tid >> 3, k4 = tid & 7;
    int node = nb + row;
    if (node >= n) return;
    float s0 = 0.f, s1 = 0.f, s2 = 0.f, s3 = 0.f;
#pragma unroll 8
    for (int i = 0; i < 256; ++i) {
        float xv = xs[row * 260 + i];
        float4 w = *reinterpret_cast<const float4*>(&W1[i * 32 + k4 * 4]);
        s0 += xv * w.x; s1 += xv * w.y; s2 += xv * w.z; s3 += xv * w.w;
    }
    float d = dinv[node];
    *reinterpret_cast<float4*>(&g1[(size_t)node * 32 + k4 * 4]) =
        make_float4(d * s0, d * s1, d * s2, d * s3);
}

// layer-1 aggregate (CSR gather, float4 lanes, 4-wide): g2 = dinv.relu(dinv*(sum)+b1)
__launch_bounds__(256)
__global__ void k_agg1(const float4* __restrict__ g1_4, const unsigned* __restrict__ erow,
                       const int* __restrict__ ptr, const float* __restrict__ dinv,
                       const float* __restrict__ b1, float4* __restrict__ g2_4, int n) {
    int tid = threadIdx.x;
    int g = tid >> 3, l = tid & 7;
    int node = blockIdx.x * 32 + g;
    if (node >= n) return;
    int s = ptr[node], e = ptr[node + 1];
    float4 a0 = g1_4[(size_t)node * 8 + l];   // self-loop
    float4 a1 = make_float4(0.f, 0.f, 0.f, 0.f), a2 = a1, a3 = a1;
    int t = s;
    for (; t + 3 < e; t += 4) {
        int r0 = erow[t], r1 = erow[t + 1], r2 = erow[t + 2], r3 = erow[t + 3];
        float4 v0 = g1_4[(size_t)r0 * 8 + l];
        float4 v1 = g1_4[(size_t)r1 * 8 + l];
        float4 v2 = g1_4[(size_t)r2 * 8 + l];
        float4 v3 = g1_4[(size_t)r3 * 8 + l];
        a0 = add4(a0, v0); a1 = add4(a1, v1); a2 = add4(a2, v2); a3 = add4(a3, v3);
    }
    for (; t < e; ++t) a0 = add4(a0, g1_4[(size_t)erow[t] * 8 + l]);
    float4 acc = add4(add4(a0, a1), add4(a2, a3));
    float d = dinv[node];
    float4 bb = *reinterpret_cast<const float4*>(&b1[l * 4]);
    float4 h;
    h.x = fmaxf(fmaf(d, acc.x, bb.x), 0.f) * d;
    h.y = fmaxf(fmaf(d, acc.y, bb.y), 0.f) * d;
    h.z = fmaxf(fmaf(d, acc.z, bb.z), 0.f) * d;
    h.w = fmaxf(fmaf(d, acc.w, bb.w), 0.f) * d;
    g2_4[(size_t)node * 8 + l] = h;
}

// layer-2 aggregate + fused W2 projection
__launch_bounds__(256)
__global__ void k_agg2(const float4* __restrict__ g2_4, const unsigned* __restrict__ erow,
                       const int* __restrict__ ptr, const float* __restrict__ dinv,
                       const float* __restrict__ W2, const float* __restrict__ b2,
                       float* __restrict__ out, int n) {
    __shared__ float fr[32][33];
    __shared__ float w2s[32 * 64];
    int tid = threadIdx.x;
    for (int t = tid; t < 32 * 64; t += 256) w2s[t] = W2[t];
    int g = tid >> 3, l = tid & 7;
    int node = blockIdx.x * 32 + g;
    float4 v = make_float4(0.f, 0.f, 0.f, 0.f);
    if (node < n) {
        int s = ptr[node], e = ptr[node + 1];
        float4 a0 = g2_4[(size_t)node * 8 + l];
        float4 a1 = make_float4(0.f, 0.f, 0.f, 0.f), a2 = a1, a3 = a1;
        int t = s;
        for (; t + 3 < e; t += 4) {
            int r0 = erow[t], r1 = erow[t + 1], r2 = erow[t + 2], r3 = erow[t + 3];
            float4 v0 = g2_4[(size_t)r0 * 8 + l];
            float4 v1 = g2_4[(size_t)r1 * 8 + l];
            float4 v2 = g2_4[(size_t)r2 * 8 + l];
            float4 v3 = g2_4[(size_t)r3 * 8 + l];
            a0 = add4(a0, v0); a1 = add4(a1, v1); a2 = add4(a2, v2); a3 = add4(a3, v3);
        }
        for (; t < e; ++t) a0 = add4(a0, g2_4[(size_t)erow[t] * 8 + l]);
        float4 acc = add4(add4(a0, a1), add4(a2, a3));
        float d = dinv[node];
        v = make_float4(d * acc.x, d * acc.y, d * acc.z, d * acc.w);
    }
    fr[g][l * 4 + 0] = v.x;
    fr[g][l * 4 + 1] = v.y;
    fr[g][l * 4 + 2] = v.z;
    fr[g][l * 4 + 3] = v.w;
    __syncthreads();
    int j = tid & 63, mg = tid >> 6;     // 4 waves x 8 nodes
    for (int mm = 0; mm < 8; ++mm) {
        int m = mg * 8 + mm;
        int node2 = blockIdx.x * 32 + m;
        if (node2 >= n) continue;
        float sacc = b2[j];
#pragma unroll
        for (int i = 0; i < 32; ++i)
            sacc = fmaf(fr[m][i], w2s[i * 64 + j], sacc);
        out[(size_t)node2 * 64 + j] = sacc;
    }
}

extern "C" void kernel_launch(void* const* d_in, const int* in_sizes, int n_in,
                              void* d_out, int out_size, void* d_ws, size_t ws_size,
                              hipStream_t stream) {
    const float* x  = (const float*)d_in[0];
    const int*   ei = (const int*)d_in[1];
    const float* W1 = (const float*)d_in[2];
    const float* b1 = (const float*)d_in[3];
    const float* W2 = (const float*)d_in[4];
    const float* b2 = (const float*)d_in[5];
    float* out = (float*)d_out;

    const int N = in_sizes[0] / 256;
    const int E = in_sizes[1] / 2;
    const int* rows = ei;        // edge_index[0] (source)
    const int* cols = ei + E;    // edge_index[1] (dest)
    const int NB = (N + S - 1) >> SHIFT;   // 1563 buckets

    // ws layout (4B units):
    // pk[E] | g1[N*32] | g2[N*32] | dinv[N] | ptr[N+1] | bptr[NB+1] | bcnt[NB] | bfill[NB]
    unsigned* pk = (unsigned*)d_ws;
    float* g1    = (float*)(pk + E);
    float* g2    = g1 + (size_t)N * 32;
    float* dinv  = g2 + (size_t)N * 32;
    int*   ptr   = (int*)(dinv + N);
    int*   bptr  = ptr + (N + 1);
    int*   bcnt  = bptr + (NB + 1);
    int*   bfill = bcnt + NB;

    const int B = 256;
    const int chunk = (E + 255) / 256;
    const int nblk = (N + 31) / 32;

    k_zero<<<(NB + B - 1) / B, B, 0, stream>>>(bcnt, NB);
    k_bhist<<<256, B, 0, stream>>>(cols, bcnt, E, NB);
    k_bscan<<<1, 1024, 0, stream>>>(bcnt, bptr, bfill, NB, E);
    k_bscatter<<<256, B, 0, stream>>>(rows, cols, bfill, pk, E, NB, chunk);
    k_fine<<<NB, B, 0, stream>>>(pk, bptr, ptr, dinv, N, NB);
    k_xw_g<<<(N + 31) / 32, B, 0, stream>>>((const float4*)x, W1, dinv, g1, N);
    k_agg1<<<nblk, B, 0, stream>>>((const float4*)g1, pk, ptr, dinv, b1, (float4*)g2, N);
    k_agg2<<<nblk, B, 0, stream>>>((const float4*)g2, pk, ptr, dinv, W2, b2, out, N);
}

// Round 5
// 281.907 us; speedup vs baseline: 5.1230x; 1.1892x over previous
//
#include <hip/hip_runtime.h>
#include <math.h>

// GCN 2-layer on MI355X. N=100000, E=3200000, F_IN=256, HID=32, F_OUT=64.
// Pipeline: coarse bucket sort by dest (write-combined, packed row<<6|col6),
// per-bucket LDS fine sort -> per-node CSR + dinv, then gather-based
// aggregations (float4 lanes, 4-wide unroll). No global float atomics.
// dinv folded into source: agg(h)[i] = dinv[i]*(sum_{j->i} g[j] + g[i]), g = dinv.h

#define SHIFT 6
#define S 64
#define MAXNB 1600
#define CAP 6144

__device__ inline float4 add4(float4 a, float4 b) {
    return make_float4(a.x + b.x, a.y + b.y, a.z + b.z, a.w + b.w);
}

__global__ void k_zero(int* p, int n) {
    int i = blockIdx.x * blockDim.x + threadIdx.x;
    if (i < n) p[i] = 0;
}

// global bucket counts via per-block LDS histogram
__global__ void k_bhist(const int* __restrict__ cols, int* __restrict__ bcnt,
                        int e, int nb) {
    __shared__ int h[MAXNB];
    for (int i = threadIdx.x; i < nb; i += blockDim.x) h[i] = 0;
    __syncthreads();
    for (int i = blockIdx.x * blockDim.x + threadIdx.x; i < e; i += gridDim.x * blockDim.x)
        atomicAdd(&h[cols[i] >> SHIFT], 1);
    __syncthreads();
    for (int i = threadIdx.x; i < nb; i += blockDim.x)
        if (h[i]) atomicAdd(&bcnt[i], h[i]);
}

// exclusive scan of nb (<=2048) bucket counts
__global__ void k_bscan(const int* __restrict__ bcnt, int* __restrict__ bptr,
                        int* __restrict__ bfill, int nb, int e) {
    __shared__ int sh[1024];
    int tid = threadIdx.x;
    int a = (2 * tid     < nb) ? bcnt[2 * tid]     : 0;
    int b = (2 * tid + 1 < nb) ? bcnt[2 * tid + 1] : 0;
    sh[tid] = a + b;
    __syncthreads();
    for (int off = 1; off < 1024; off <<= 1) {
        int t = (tid >= off) ? sh[tid - off] : 0;
        __syncthreads();
        sh[tid] += t;
        __syncthreads();
    }
    int excl = sh[tid] - (a + b);
    if (2 * tid < nb)     { bptr[2 * tid] = excl;         bfill[2 * tid] = excl; }
    if (2 * tid + 1 < nb) { bptr[2 * tid + 1] = excl + a; bfill[2 * tid + 1] = excl + a; }
    if (tid == 0) bptr[nb] = e;
}

// bucket the edges, packed (row<<6)|(col&63); per-block reservation so each
// bucket range is written in sequential runs (write combining)
__global__ void k_bscatter(const int* __restrict__ rows, const int* __restrict__ cols,
                           int* bfill, unsigned* __restrict__ pk, int e, int nb, int chunk) {
    __shared__ int hist[MAXNB];
    int tid = threadIdx.x;
    for (int i = tid; i < nb; i += blockDim.x) hist[i] = 0;
    __syncthreads();
    int start = blockIdx.x * chunk;
    int end = min(e, start + chunk);
    for (int i = start + tid; i < end; i += blockDim.x)
        atomicAdd(&hist[cols[i] >> SHIFT], 1);
    __syncthreads();
    for (int i = tid; i < nb; i += blockDim.x) {
        int c = hist[i];
        if (c) hist[i] = atomicAdd(&bfill[i], c);   // hist[] becomes per-block base
    }
    __syncthreads();
    for (int i = start + tid; i < end; i += blockDim.x) {
        int r = rows[i], c = cols[i];
        int pos = atomicAdd(&hist[c >> SHIFT], 1);
        pk[pos] = ((unsigned)r << SHIFT) | (unsigned)(c & (S - 1));
    }
}

// per-bucket fine sort: histogram -> scan -> stage rows sorted-by-node in LDS
// -> contiguous in-place write-back. Also emits per-node CSR ptr + dinv.
__global__ void k_fine(unsigned* pk, const int* __restrict__ bptr,
                       int* __restrict__ ptr, float* __restrict__ dinv, int n, int nb) {
    __shared__ int cnt[S], base[S], fill[S];
    __shared__ int stage[CAP];
    int tid = threadIdx.x, b = blockIdx.x;
    if (tid < S) cnt[tid] = 0;
    __syncthreads();
    int s = bptr[b], e = bptr[b + 1], L = e - s;
    for (int t = s + tid; t < e; t += 256) atomicAdd(&cnt[pk[t] & (S - 1)], 1);
    __syncthreads();
    if (tid == 0) {
        int run = 0;
        for (int i = 0; i < S; ++i) { base[i] = run; fill[i] = run; run += cnt[i]; }
    }
    __syncthreads();
    if (tid < S) {
        int node = (b << SHIFT) + tid;
        if (node < n) {
            ptr[node] = s + base[tid];
            dinv[node] = rsqrtf((float)(cnt[tid] + 1));
        }
    }
    if (tid == 0 && b == nb - 1) ptr[n] = e;
    for (int t = s + tid; t < e; t += 256) {
        unsigned p = pk[t];
        int pos = atomicAdd(&fill[p & (S - 1)], 1);
        if (pos < CAP) stage[pos] = (int)(p >> SHIFT);
    }
    __syncthreads();
    int M = L < CAP ? L : CAP;
    for (int i = tid; i < M; i += 256) pk[s + i] = (unsigned)stage[i];
}

// g1 = dinv (.) (x @ W1): LDS-tiled (x tile AND W1 in LDS), 32 nodes/block.
// Inner loop is pure LDS: per 4 K-steps, 1 b128 (x) + 4 b128 (W1) + 16 FMA.
__launch_bounds__(256)
__global__ void k_xw_g(const float4* __restrict__ x4, const float4* __restrict__ W1_4,
                       const float* __restrict__ dinv, float* __restrict__ g1, int n) {
    __shared__ float xs[32 * 260];     // 32 rows, stride 260: float4-aligned, bank-clean
    __shared__ float w1s[256 * 32];    // 32 KB
    int tid = threadIdx.x;
    int nb = blockIdx.x * 32;
#pragma unroll
    for (int t = 0; t < 8; ++t) {
        int idx = tid + t * 256;           // float4 idx in 32x64 tile
        int row = idx >> 6, c4 = idx & 63;
        float4 v = (nb + row < n) ? x4[(size_t)(nb + row) * 64 + c4]
                                  : make_float4(0.f, 0.f, 0.f, 0.f);
        *reinterpret_cast<float4*>(&xs[row * 260 + c4 * 4]) = v;
        *reinterpret_cast<float4*>(&w1s[idx * 4]) = W1_4[idx];   // 2048 float4 = W1
    }
    __syncthreads();
    int row = tid >> 3, k4 = tid & 7;
    int node = nb + row;
    if (node >= n) return;
    float s0 = 0.f, s1 = 0.f, s2 = 0.f, s3 = 0.f;
#pragma unroll 4
    for (int i4 = 0; i4 < 64; ++i4) {
        float4 xv = *reinterpret_cast<const float4*>(&xs[row * 260 + i4 * 4]);
#pragma unroll
        for (int c = 0; c < 4; ++c) {
            float xc = c == 0 ? xv.x : c == 1 ? xv.y : c == 2 ? xv.z : xv.w;
            float4 w = *reinterpret_cast<const float4*>(&w1s[(i4 * 4 + c) * 32 + k4 * 4]);
            s0 = fmaf(xc, w.x, s0); s1 = fmaf(xc, w.y, s1);
            s2 = fmaf(xc, w.z, s2); s3 = fmaf(xc, w.w, s3);
        }
    }
    float d = dinv[node];
    *reinterpret_cast<float4*>(&g1[(size_t)node * 32 + k4 * 4]) =
        make_float4(d * s0, d * s1, d * s2, d * s3);
}

// layer-1 aggregate (CSR gather, float4 lanes, 4-wide): g2 = dinv.relu(dinv*(sum)+b1)
__launch_bounds__(256)
__global__ void k_agg1(const float4* __restrict__ g1_4, const unsigned* __restrict__ erow,
                       const int* __restrict__ ptr, const float* __restrict__ dinv,
                       const float* __restrict__ b1, float4* __restrict__ g2_4, int n) {
    int tid = threadIdx.x;
    int g = tid >> 3, l = tid & 7;
    int node = blockIdx.x * 32 + g;
    if (node >= n) return;
    int s = ptr[node], e = ptr[node + 1];
    float4 a0 = g1_4[(size_t)node * 8 + l];   // self-loop
    float4 a1 = make_float4(0.f, 0.f, 0.f, 0.f), a2 = a1, a3 = a1;
    int t = s;
    for (; t + 3 < e; t += 4) {
        int r0 = erow[t], r1 = erow[t + 1], r2 = erow[t + 2], r3 = erow[t + 3];
        float4 v0 = g1_4[(size_t)r0 * 8 + l];
        float4 v1 = g1_4[(size_t)r1 * 8 + l];
        float4 v2 = g1_4[(size_t)r2 * 8 + l];
        float4 v3 = g1_4[(size_t)r3 * 8 + l];
        a0 = add4(a0, v0); a1 = add4(a1, v1); a2 = add4(a2, v2); a3 = add4(a3, v3);
    }
    for (; t < e; ++t) a0 = add4(a0, g1_4[(size_t)erow[t] * 8 + l]);
    float4 acc = add4(add4(a0, a1), add4(a2, a3));
    float d = dinv[node];
    float4 bb = *reinterpret_cast<const float4*>(&b1[l * 4]);
    float4 h;
    h.x = fmaxf(fmaf(d, acc.x, bb.x), 0.f) * d;
    h.y = fmaxf(fmaf(d, acc.y, bb.y), 0.f) * d;
    h.z = fmaxf(fmaf(d, acc.z, bb.z), 0.f) * d;
    h.w = fmaxf(fmaf(d, acc.w, bb.w), 0.f) * d;
    g2_4[(size_t)node * 8 + l] = h;
}

// layer-2 aggregate + fused W2 projection
__launch_bounds__(256)
__global__ void k_agg2(const float4* __restrict__ g2_4, const unsigned* __restrict__ erow,
                       const int* __restrict__ ptr, const float* __restrict__ dinv,
                       const float* __restrict__ W2, const float* __restrict__ b2,
                       float* __restrict__ out, int n) {
    __shared__ float fr[32][33];
    __shared__ float w2s[32 * 64];
    int tid = threadIdx.x;
    for (int t = tid; t < 32 * 64; t += 256) w2s[t] = W2[t];
    int g = tid >> 3, l = tid & 7;
    int node = blockIdx.x * 32 + g;
    float4 v = make_float4(0.f, 0.f, 0.f, 0.f);
    if (node < n) {
        int s = ptr[node], e = ptr[node + 1];
        float4 a0 = g2_4[(size_t)node * 8 + l];
        float4 a1 = make_float4(0.f, 0.f, 0.f, 0.f), a2 = a1, a3 = a1;
        int t = s;
        for (; t + 3 < e; t += 4) {
            int r0 = erow[t], r1 = erow[t + 1], r2 = erow[t + 2], r3 = erow[t + 3];
            float4 v0 = g2_4[(size_t)r0 * 8 + l];
            float4 v1 = g2_4[(size_t)r1 * 8 + l];
            float4 v2 = g2_4[(size_t)r2 * 8 + l];
            float4 v3 = g2_4[(size_t)r3 * 8 + l];
            a0 = add4(a0, v0); a1 = add4(a1, v1); a2 = add4(a2, v2); a3 = add4(a3, v3);
        }
        for (; t < e; ++t) a0 = add4(a0, g2_4[(size_t)erow[t] * 8 + l]);
        float4 acc = add4(add4(a0, a1), add4(a2, a3));
        float d = dinv[node];
        v = make_float4(d * acc.x, d * acc.y, d * acc.z, d * acc.w);
    }
    fr[g][l * 4 + 0] = v.x;
    fr[g][l * 4 + 1] = v.y;
    fr[g][l * 4 + 2] = v.z;
    fr[g][l * 4 + 3] = v.w;
    __syncthreads();
    int j = tid & 63, mg = tid >> 6;     // 4 waves x 8 nodes
    for (int mm = 0; mm < 8; ++mm) {
        int m = mg * 8 + mm;
        int node2 = blockIdx.x * 32 + m;
        if (node2 >= n) continue;
        float sacc = b2[j];
#pragma unroll
        for (int i = 0; i < 32; ++i)
            sacc = fmaf(fr[m][i], w2s[i * 64 + j], sacc);
        out[(size_t)node2 * 64 + j] = sacc;
    }
}

extern "C" void kernel_launch(void* const* d_in, const int* in_sizes, int n_in,
                              void* d_out, int out_size, void* d_ws, size_t ws_size,
                              hipStream_t stream) {
    const float* x  = (const float*)d_in[0];
    const int*   ei = (const int*)d_in[1];
    const float* W1 = (const float*)d_in[2];
    const float* b1 = (const float*)d_in[3];
    const float* W2 = (const float*)d_in[4];
    const float* b2 = (const float*)d_in[5];
    float* out = (float*)d_out;

    const int N = in_sizes[0] / 256;
    const int E = in_sizes[1] / 2;
    const int* rows = ei;        // edge_index[0] (source)
    const int* cols = ei + E;    // edge_index[1] (dest)
    const int NB = (N + S - 1) >> SHIFT;   // 1563 buckets

    // ws layout (4B units):
    // pk[E] | g1[N*32] | g2[N*32] | dinv[N] | ptr[N+1] | bptr[NB+1] | bcnt[NB] | bfill[NB]
    unsigned* pk = (unsigned*)d_ws;
    float* g1    = (float*)(pk + E);
    float* g2    = g1 + (size_t)N * 32;
    float* dinv  = g2 + (size_t)N * 32;
    int*   ptr   = (int*)(dinv + N);
    int*   bptr  = ptr + (N + 1);
    int*   bcnt  = bptr + (NB + 1);
    int*   bfill = bcnt + NB;

    const int B = 256;
    const int chunk = (E + 255) / 256;
    const int nblk = (N + 31) / 32;

    k_zero<<<(NB + B - 1) / B, B, 0, stream>>>(bcnt, NB);
    k_bhist<<<256, B, 0, stream>>>(cols, bcnt, E, NB);
    k_bscan<<<1, 1024, 0, stream>>>(bcnt, bptr, bfill, NB, E);
    k_bscatter<<<256, B, 0, stream>>>(rows, cols, bfill, pk, E, NB, chunk);
    k_fine<<<NB, B, 0, stream>>>(pk, bptr, ptr, dinv, N, NB);
    k_xw_g<<<(N + 31) / 32, B, 0, stream>>>((const float4*)x, (const float4*)W1, dinv, g1, N);
    k_agg1<<<nblk, B, 0, stream>>>((const float4*)g1, pk, ptr, dinv, b1, (float4*)g2, N);
    k_agg2<<<nblk, B, 0, stream>>>((const float4*)g2, pk, ptr, dinv, W2, b2, out, N);
}